// Round 1
// baseline (245.463 us; speedup 1.0000x reference)
//
#include <hip/hip_runtime.h>
#include <hip/hip_bf16.h>

// FacePartGAT: dense-graph GATConv x2 + mean + fc on MI355X. ALL I/O fp32.
// e[i,j] = leaky_relu(t_i + s_j) => softmax aggregation factorizes after
// sorting sources by s_j (prefix/suffix tables + binary search). Exact.
// Round 12: dispatch-count reduction (17 -> 12).
//  - s/t fused into GEMM epilogues (shfl_xor col-reduce + atomicAdd; s/t
//    zeroed in prep). Removes st_kernel x2 and 10.5 MB of h re-reads.
//  - one-kernel rank sort: all 4096 keys in LDS (16 KB), 32 nodes/block x
//    8 partial scans, LDS combine, direct scatter. Removes scatter pass.
//  - mean+fc fused via fence+counter last-block pattern (agent-scope
//    atomics -> XCD-safe, no co-residency assumption).

#define NNODE 4096
#define CDIM 128
#define TW 132           // table width: 128 features + z at col 128
#define NEG 0.2f
#define CHUNK 64
#define NCHUNK 64        // NNODE / CHUNK

typedef __bf16 bf16x8 __attribute__((ext_vector_type(8)));
typedef float f32x4 __attribute__((ext_vector_type(4)));

__device__ __forceinline__ unsigned short f2b(float f) {
  unsigned int u = __float_as_uint(f);
  u += 0x7fffu + ((u >> 16) & 1u);  // RTNE
  return (unsigned short)(u >> 16);
}

// One kernel: [0,3072) convert x -> bf16; [3072,3168) W1 transpose;
// [3168,3184) W2 transpose; [3184,3216) zero s1/t1; [3216,3224) zero s2/t2;
// [3224] zero mv+counter.
__global__ __launch_bounds__(256) void prep_kernel(const float* __restrict__ x,
                                                   const float* __restrict__ W1,
                                                   const float* __restrict__ W2,
                                                   unsigned short* __restrict__ xb,
                                                   unsigned short* __restrict__ W1t,
                                                   unsigned short* __restrict__ W2t,
                                                   float* __restrict__ zs1,
                                                   float* __restrict__ zs2,
                                                   float* __restrict__ zfc) {
  __shared__ float tile[64][65];
  int b = blockIdx.x, t = threadIdx.x;
  if (b < 3072) {  // convert x: 4096*768/4 quads
    int i = b * 256 + t;
    float4 v = ((const float4*)x)[i];
    ushort4 o;
    o.x = f2b(v.x); o.y = f2b(v.y); o.z = f2b(v.z); o.w = f2b(v.w);
    ((ushort4*)xb)[i] = o;
    return;
  }
  if (b >= 3184) {  // zero regions
    float4 z = {0.f, 0.f, 0.f, 0.f};
    if (b < 3216) {
      ((float4*)zs1)[(b - 3184) * 256 + t] = z;       // s1+t1: 32768 floats
    } else if (b < 3224) {
      ((float4*)zs2)[(b - 3216) * 256 + t] = z;       // s2+t2: 8192 floats
    } else if (t < 64) {
      ((float4*)zfc)[t] = z;                          // mv + counter: 256 floats
    }
    return;
  }
  const float* W; unsigned short* Wt; int K, N, n0, k0;
  if (b < 3072 + 96) {  // W1 [768,512] -> W1t [512,768]
    int b2 = b - 3072; W = W1; Wt = W1t; K = 768; N = 512;
    n0 = (b2 & 7) * 64; k0 = (b2 >> 3) * 64;
  } else {              // W2 [512,128] -> W2t [128,512]
    int b3 = b - 3072 - 96; W = W2; Wt = W2t; K = 512; N = 128;
    n0 = (b3 & 1) * 64; k0 = (b3 >> 1) * 64;
  }
  for (int p = 0; p < 16; p++) {
    int e = p * 256 + t;
    int rr = e >> 6, cc = e & 63;
    tile[rr][cc] = W[(size_t)(k0 + rr) * N + n0 + cc];
  }
  __syncthreads();
  for (int p = 0; p < 16; p++) {
    int e = p * 256 + t;
    int rr = e >> 6, cc = e & 63;  // rr: n-dir, cc: k-dir
    Wt[(size_t)(n0 + rr) * K + k0 + cc] = f2b(tile[cc][rr]);
  }
}

// C[M,N] = A[M,K] x Bt[N,K]^T, both bf16 K-contig. BK=32, 256 thr = 4 waves
// (2x2). Register prefetch of tile k+1 between LDS barrier and MFMA.
// Fused epilogue: s[h][n] / t[h][n] partial dot products from acc registers
// (col-reduce over the 16-lane fm group, atomicAdd; one head per block since
// BN=64 and head width 128).
template <int BM, int BN>
__global__ __launch_bounds__(256) void mfma_gemm_bt(const unsigned short* __restrict__ A,
                                                    const unsigned short* __restrict__ Bt,
                                                    float* __restrict__ C,
                                                    int M, int N, int K,
                                                    float* __restrict__ sAcc,
                                                    float* __restrict__ tAcc,
                                                    const float* __restrict__ av_s,
                                                    const float* __restrict__ av_d) {
  __shared__ __align__(16) unsigned short As[BM * 40];
  __shared__ __align__(16) unsigned short Bs[BN * 40];
  constexpr int WM = BM / 2, WN = BN / 2;
  constexpr int FI = WM / 16, FJ = WN / 16;
  constexpr int EA = BM * 32 / 8;
  constexpr int EB = BN * 32 / 8;
  constexpr int NA = (EA + 255) / 256;
  constexpr int NB = (EB + 255) / 256;
  int tid = threadIdx.x;
  int lane = tid & 63, wave = tid >> 6;
  int wm = (wave >> 1) * WM, wn = (wave & 1) * WN;
  int m0 = blockIdx.y * BM, n0 = blockIdx.x * BN;
  int fm = lane & 15, fq = lane >> 4;
  f32x4 acc[FI][FJ] = {};
  uint4 ar[NA], br[NB];
  // preload tile 0
#pragma unroll
  for (int q = 0; q < NA; q++) {
    int e = q * 256 + tid;
    if (e < EA) {
      int r = e >> 2, kk = (e & 3) * 8;
      ar[q] = *(const uint4*)(A + (size_t)(m0 + r) * K + kk);
    }
  }
#pragma unroll
  for (int q = 0; q < NB; q++) {
    int e = q * 256 + tid;
    if (e < EB) {
      int r = e >> 2, kk = (e & 3) * 8;
      br[q] = *(const uint4*)(Bt + (size_t)(n0 + r) * K + kk);
    }
  }
  for (int k0 = 0; k0 < K; k0 += 32) {
    __syncthreads();  // previous iter's ds_reads done before overwrite
#pragma unroll
    for (int q = 0; q < NA; q++) {
      int e = q * 256 + tid;
      if (e < EA) {
        int r = e >> 2, kk = (e & 3) * 8;
        *(uint4*)&As[r * 40 + kk] = ar[q];
      }
    }
#pragma unroll
    for (int q = 0; q < NB; q++) {
      int e = q * 256 + tid;
      if (e < EB) {
        int r = e >> 2, kk = (e & 3) * 8;
        *(uint4*)&Bs[r * 40 + kk] = br[q];
      }
    }
    __syncthreads();
    // prefetch tile k+1 (in flight during ds_read + MFMA below)
    if (k0 + 32 < K) {
#pragma unroll
      for (int q = 0; q < NA; q++) {
        int e = q * 256 + tid;
        if (e < EA) {
          int r = e >> 2, kk = (e & 3) * 8;
          ar[q] = *(const uint4*)(A + (size_t)(m0 + r) * K + k0 + 32 + kk);
        }
      }
#pragma unroll
      for (int q = 0; q < NB; q++) {
        int e = q * 256 + tid;
        if (e < EB) {
          int r = e >> 2, kk = (e & 3) * 8;
          br[q] = *(const uint4*)(Bt + (size_t)(n0 + r) * K + k0 + 32 + kk);
        }
      }
    }
    bf16x8 af[FI], bfr[FJ];
#pragma unroll
    for (int i = 0; i < FI; i++)
      af[i] = *(const bf16x8*)&As[(wm + i * 16 + fm) * 40 + fq * 8];
#pragma unroll
    for (int j = 0; j < FJ; j++)
      bfr[j] = *(const bf16x8*)&Bs[(wn + j * 16 + fm) * 40 + fq * 8];
#pragma unroll
    for (int i = 0; i < FI; i++)
#pragma unroll
      for (int j = 0; j < FJ; j++)
        acc[i][j] = __builtin_amdgcn_mfma_f32_16x16x32_bf16(af[i], bfr[j], acc[i][j], 0, 0, 0);
  }
  // C store
#pragma unroll
  for (int i = 0; i < FI; i++) {
#pragma unroll
    for (int j = 0; j < FJ; j++) {
      int r = m0 + wm + i * 16 + fq * 4;
      int ccol = n0 + wn + j * 16 + fm;
#pragma unroll
      for (int reg = 0; reg < 4; reg++)
        C[(size_t)(r + reg) * N + ccol] = acc[i][j][reg];
    }
  }
  // fused s/t epilogue: row-dot with att vectors. Block spans one head
  // (BN=64, head width 128). av_* indexed by global col (= h*CDIM + c).
  {
    int hh = n0 >> 7;
    float avs[FJ], avd[FJ];
#pragma unroll
    for (int j = 0; j < FJ; j++) {
      int col = n0 + wn + j * 16 + fm;
      avs[j] = av_s[col];
      avd[j] = av_d[col];
    }
#pragma unroll
    for (int i = 0; i < FI; i++) {
#pragma unroll
      for (int reg = 0; reg < 4; reg++) {
        float sv = 0.f, tv = 0.f;
#pragma unroll
        for (int j = 0; j < FJ; j++) {
          sv = fmaf(acc[i][j][reg], avs[j], sv);
          tv = fmaf(acc[i][j][reg], avd[j], tv);
        }
#pragma unroll
        for (int o = 1; o < 16; o <<= 1) {
          sv += __shfl_xor(sv, o, 64);
          tv += __shfl_xor(tv, o, 64);
        }
        if (fm == 0) {
          int row = m0 + wm + i * 16 + fq * 4 + reg;
          atomicAdd(&sAcc[(size_t)hh * NNODE + row], sv);
          atomicAdd(&tAcc[(size_t)hh * NNODE + row], tv);
        }
      }
    }
  }
}

// One-kernel rank sort: all 4096 keys staged in LDS (16 KB). Block = 32
// nodes x 8 scan-parts of 512 keys; partial counts combined in LDS; direct
// scatter of (key, idx) to sorted position. Key reads are wave-uniform per
// 32-lane half -> LDS broadcast, conflict-free.
__global__ __launch_bounds__(256) void rank_sort_kernel(const float* __restrict__ s,
                                                        float* __restrict__ ss,
                                                        int* __restrict__ si) {
  __shared__ __align__(16) float keys[NNODE];
  __shared__ int pc[8][32];
  int hh = blockIdx.y, tid = threadIdx.x;
  const float* sp = s + (size_t)hh * NNODE;
  for (int k = tid; k < NNODE / 4; k += 256)
    ((float4*)keys)[k] = ((const float4*)sp)[k];
  __syncthreads();
  int slot = tid & 31, part = tid >> 5;
  int node = blockIdx.x * 32 + slot;
  float mk = keys[node];
  int cnt = 0;
  int j0 = part * 512;
#pragma unroll 4
  for (int j = j0; j < j0 + 512; j += 4) {
    float4 kv = *(const float4*)&keys[j];
    cnt += (kv.x < mk) || (kv.x == mk && (j + 0) < node);
    cnt += (kv.y < mk) || (kv.y == mk && (j + 1) < node);
    cnt += (kv.z < mk) || (kv.z == mk && (j + 2) < node);
    cnt += (kv.w < mk) || (kv.w == mk && (j + 3) < node);
  }
  pc[part][slot] = cnt;
  __syncthreads();
  if (tid < 32) {
    int rank = 0;
#pragma unroll
    for (int p = 0; p < 8; p++) rank += pc[p][tid];
    int n2 = blockIdx.x * 32 + tid;
    ss[(size_t)hh * NNODE + rank] = keys[n2];
    si[(size_t)hh * NNODE + rank] = n2;
  }
}

// Pass A: per-chunk partial sums of e^{s}*h (P) and e^{0.2s}*h (M); z at 128.
__global__ __launch_bounds__(128) void passA_kernel(const float* __restrict__ h,
                                                    const float* __restrict__ ss,
                                                    const int* __restrict__ si,
                                                    float* __restrict__ partP,
                                                    float* __restrict__ partM, int H) {
  __shared__ float eP[CHUNK], eM[CHUNK];
  __shared__ int ids[CHUNK];
  int b = blockIdx.x, hh = b / NCHUNK, ci = b % NCHUNK;
  int c = threadIdx.x;
  int HC = H * CDIM;
  int base = ci * CHUNK;
  if (c < CHUNK) {
    float sv = ss[(size_t)hh * NNODE + base + c];
    ids[c] = si[(size_t)hh * NNODE + base + c];
    eP[c] = expf(sv);
    eM[c] = expf(NEG * sv);
  }
  __syncthreads();
  float sp = 0.f, sm = 0.f;
  for (int kb = 0; kb < CHUNK; kb += 8) {
    float v[8];
#pragma unroll
    for (int j = 0; j < 8; j++)
      v[j] = h[(size_t)ids[kb + j] * HC + hh * CDIM + c];
#pragma unroll
    for (int j = 0; j < 8; j++) {
      sp = fmaf(eP[kb + j], v[j], sp);
      sm = fmaf(eM[kb + j], v[j], sm);
    }
  }
  size_t o = ((size_t)hh * NCHUNK + ci) * TW;
  partP[o + c] = sp;
  partM[o + c] = sm;
  if (c == 0) {
    float zp = 0.f, zm = 0.f;
#pragma unroll
    for (int k = 0; k < CHUNK; k++) { zp += eP[k]; zm += eM[k]; }
    partP[o + 128] = zp;
    partM[o + 128] = zm;
  }
}

// Pass C with fused BATCHED carry combine (16 independent loads in flight).
// LDS-staged gather + dual scan, z at col 128.
__global__ __launch_bounds__(128) void passC_kernel(const float* __restrict__ h,
                                                    const float* __restrict__ ss,
                                                    const int* __restrict__ si,
                                                    const float* __restrict__ partP,
                                                    const float* __restrict__ partM,
                                                    float* __restrict__ SS,
                                                    float* __restrict__ PP, int H) {
  __shared__ float hrow[CHUNK][CDIM];  // 32 KB
  __shared__ float eP[CHUNK], eM[CHUNK];
  __shared__ int ids[CHUNK];
  int b = blockIdx.x, hh = b / NCHUNK, ci = b % NCHUNK;
  int c = threadIdx.x;
  int HC = H * CDIM;
  int base = ci * CHUNK;
  size_t hb = (size_t)hh * (NNODE + 1);
  if (c < CHUNK) {
    float sv = ss[(size_t)hh * NNODE + base + c];
    ids[c] = si[(size_t)hh * NNODE + base + c];
    eP[c] = expf(sv);
    eM[c] = expf(NEG * sv);
  }
  __syncthreads();
  // carry combine: feature columns (all threads), 16 loads in flight
  float cm = 0.f, cp = 0.f;
  for (int g0 = 0; g0 < NCHUNK; g0 += 16) {
    float vm[16], vp[16];
#pragma unroll
    for (int j = 0; j < 16; j++) {
      size_t o = ((size_t)hh * NCHUNK + g0 + j) * TW + c;
      vm[j] = partM[o];
      vp[j] = partP[o];
    }
#pragma unroll
    for (int j = 0; j < 16; j++) {
      if (g0 + j < ci) cm += vm[j];
      if (g0 + j > ci) cp += vp[j];
    }
  }
  // z carries (thread 0 only)
  float zcm = 0.f, zcp = 0.f;
  if (c == 0) {
    for (int g0 = 0; g0 < NCHUNK; g0 += 16) {
      float vm[16], vp[16];
#pragma unroll
      for (int j = 0; j < 16; j++) {
        size_t o = ((size_t)hh * NCHUNK + g0 + j) * TW + 128;
        vm[j] = partM[o];
        vp[j] = partP[o];
      }
#pragma unroll
      for (int j = 0; j < 16; j++) {
        if (g0 + j < ci) zcm += vm[j];
        if (g0 + j > ci) zcp += vp[j];
      }
    }
  }
  // gather h rows once into LDS (batched, per-thread column)
  for (int kb = 0; kb < CHUNK; kb += 8) {
    float v[8];
#pragma unroll
    for (int j = 0; j < 8; j++)
      v[j] = h[(size_t)ids[kb + j] * HC + hh * CDIM + c];
#pragma unroll
    for (int j = 0; j < 8; j++) hrow[kb + j][c] = v[j];
  }
  float runm = cm, runzm = zcm;
#pragma unroll 8
  for (int k = 0; k < CHUNK; k++) {
    size_t row = (hb + base + k) * TW;
    PP[row + c] = runm;
    if (c == 0) PP[row + 128] = runzm;
    runm = fmaf(eM[k], hrow[k][c], runm);
    runzm += eM[k];
  }
  if (ci == NCHUNK - 1) {
    size_t row = (hb + NNODE) * TW;
    PP[row + c] = runm;
    if (c == 0) PP[row + 128] = runzm;
  }
  float runp = cp, runzp = zcp;
#pragma unroll 8
  for (int k = CHUNK - 1; k >= 0; k--) {
    runp = fmaf(eP[k], hrow[k][c], runp);
    runzp += eP[k];
    size_t row = (hb + base + k) * TW;
    SS[row + c] = runp;
    if (c == 0) SS[row + 128] = runzp;
  }
  if (ci == NCHUNK - 1) {
    size_t row = (hb + NNODE) * TW;
    SS[row + c] = 0.f;
    if (c == 0) SS[row + 128] = 0.f;
  }
}

// Per (dest, head): binary search split point, combine tables, +bias, ELU.
template <typename OUT>
__global__ __launch_bounds__(128) void attend_kernel(const float* __restrict__ SS,
                                                     const float* __restrict__ PP,
                                                     const float* __restrict__ ss,
                                                     const float* __restrict__ tt,
                                                     const float* __restrict__ bias,
                                                     OUT* __restrict__ out, int H) {
  int b = blockIdx.x;
  int n = b / H, hh = b % H;
  int c = threadIdx.x;
  float tv = tt[(size_t)hh * NNODE + n];
  const float* sp = ss + (size_t)hh * NNODE;
  float thr = -tv;
  int lo = 0, hi = NNODE;
  while (lo < hi) { int mid = (lo + hi) >> 1; if (sp[mid] < thr) lo = mid + 1; else hi = mid; }
  size_t hb = (size_t)hh * (NNODE + 1);
  float wp = expf(tv), wm = expf(NEG * tv);
  float num = wp * SS[(hb + lo) * TW + c] + wm * PP[(hb + lo) * TW + c];
  float Z = wp * SS[(hb + lo) * TW + 128] + wm * PP[(hb + lo) * TW + 128];
  float o = num / Z + bias[hh * CDIM + c];
  float r = (o > 0.f) ? o : (expf(o) - 1.f);
  if constexpr (sizeof(OUT) == 2)
    out[(size_t)n * (H * CDIM) + hh * CDIM + c] = f2b(r);
  else
    out[(size_t)n * (H * CDIM) + hh * CDIM + c] = r;
}

// Fused mean + fc. 128 blocks: block c computes column mean -> mv[c]
// (agent-scope release store), bumps counter; the LAST finisher (old==127,
// i.e. all 128 stores are release-ordered before it) computes the fc.
__global__ __launch_bounds__(256) void mean_fc_kernel(const float* __restrict__ x,
                                                      const float* __restrict__ fcW,
                                                      const float* __restrict__ fcb,
                                                      float* __restrict__ mv,
                                                      int* __restrict__ counter,
                                                      float* __restrict__ out) {
  __shared__ float red[256];
  __shared__ float m[CDIM];
  __shared__ int lastFlag;
  int c = blockIdx.x, tid = threadIdx.x;
  float acc = 0.f;
  for (int i = tid; i < NNODE; i += 256) acc += x[(size_t)i * CDIM + c];
  red[tid] = acc; __syncthreads();
  for (int o = 128; o > 0; o >>= 1) { if (tid < o) red[tid] += red[tid + o]; __syncthreads(); }
  if (tid == 0) {
    __hip_atomic_store(&mv[c], red[0] * (1.f / NNODE), __ATOMIC_RELEASE,
                       __HIP_MEMORY_SCOPE_AGENT);
    int old = __hip_atomic_fetch_add(counter, 1, __ATOMIC_ACQ_REL,
                                     __HIP_MEMORY_SCOPE_AGENT);
    lastFlag = (old == 127);
  }
  __syncthreads();
  if (!lastFlag) return;
  if (tid < CDIM)
    m[tid] = __hip_atomic_load(&mv[tid], __ATOMIC_ACQUIRE, __HIP_MEMORY_SCOPE_AGENT);
  __syncthreads();
#pragma unroll
  for (int d0 = 0; d0 < 3; d0++) {
    int d = d0 * 256 + tid;
    float a = fcb[d];
#pragma unroll 4
    for (int c2 = 0; c2 < CDIM; c2++) a = fmaf(m[c2], fcW[c2 * 768 + d], a);
    out[d] = a;
  }
}

extern "C" void kernel_launch(void* const* d_in, const int* in_sizes, int n_in,
                              void* d_out, int out_size, void* d_ws, size_t ws_size,
                              hipStream_t stream) {
  const float* x   = (const float*)d_in[0];
  const float* W1  = (const float*)d_in[1];
  const float* as1 = (const float*)d_in[2];
  const float* ad1 = (const float*)d_in[3];
  const float* b1  = (const float*)d_in[4];
  const float* W2  = (const float*)d_in[5];
  const float* as2 = (const float*)d_in[6];
  const float* ad2 = (const float*)d_in[7];
  const float* b2  = (const float*)d_in[8];
  const float* fcW = (const float*)d_in[9];
  const float* fcb = (const float*)d_in[10];

  float* ws = (float*)d_ws;
  size_t off = 0;
  auto alloc = [&](size_t nfloats) { float* p = ws + off; off += nfloats; return p; };

  float* h1  = alloc((size_t)NNODE * 512);
  float* x2f = alloc((size_t)NNODE * 256 + 64 + 16384);  // x2b bf16 + W2t bf16
  float* h2  = alloc((size_t)NNODE * 128);
  float* x3  = alloc((size_t)NNODE * 128);
  float* s1  = alloc((size_t)4 * NNODE);
  float* t1  = alloc((size_t)4 * NNODE);
  float* sS1 = alloc((size_t)4 * NNODE);
  int*   sI1 = (int*)alloc((size_t)4 * NNODE);
  float* SS1 = alloc((size_t)4 * (NNODE + 1) * TW);
  float* PP1 = alloc((size_t)4 * (NNODE + 1) * TW);
  float* pP1 = alloc((size_t)4 * NCHUNK * TW);
  float* pM1 = alloc((size_t)4 * NCHUNK * TW);
  float* s2  = alloc(NNODE);
  float* t2  = alloc(NNODE);
  float* sS2 = alloc(NNODE);
  int*   sI2 = (int*)alloc(NNODE);
  float* SS2 = alloc((size_t)(NNODE + 1) * TW);
  float* PP2 = alloc((size_t)(NNODE + 1) * TW);
  float* pP2 = alloc((size_t)NCHUNK * TW);
  float* pM2 = alloc((size_t)NCHUNK * TW);
  float* fcaux = alloc(256);  // mv[128] + counter + pad

  float* mv = fcaux;
  int* counter = (int*)(fcaux + 128);

  // bf16 staging aliased into PP1/SS1 (first written by passC1, strictly after
  // gemm1 last reads them — stream ordered).
  unsigned short* xb  = (unsigned short*)PP1;  // 4096x768 bf16 = 6.3 MB (< 8.65 MB)
  unsigned short* W1t = (unsigned short*)SS1;  // 512x768 bf16
  unsigned short* x2b = (unsigned short*)x2f;                       // 4096x512 bf16
  unsigned short* W2t = (unsigned short*)(x2f + NNODE * 256 + 64);  // 128x512 bf16

  // Prep: convert x + transpose/cast W1, W2 + zero s/t accumulators & fc aux
  prep_kernel<<<3225, 256, 0, stream>>>(x, W1, W2, xb, W1t, W2t, s1, s2, fcaux);
  // Layer 1 (64x64 tiles -> 512 blocks; fused s/t epilogue)
  mfma_gemm_bt<64, 64><<<dim3(512 / 64, NNODE / 64), 256, 0, stream>>>(
      xb, W1t, h1, NNODE, 512, 768, s1, t1, as1, ad1);
  rank_sort_kernel<<<dim3(NNODE / 32, 4), 256, 0, stream>>>(s1, sS1, sI1);
  passA_kernel<<<4 * NCHUNK, 128, 0, stream>>>(h1, sS1, sI1, pP1, pM1, 4);
  passC_kernel<<<4 * NCHUNK, 128, 0, stream>>>(h1, sS1, sI1, pP1, pM1, SS1, PP1, 4);
  attend_kernel<unsigned short><<<NNODE * 4, 128, 0, stream>>>(SS1, PP1, sS1, t1, b1, x2b, 4);
  // Layer 2 (32x64 tiles -> 256 blocks; fused s/t epilogue)
  mfma_gemm_bt<32, 64><<<dim3(128 / 64, NNODE / 32), 256, 0, stream>>>(
      x2b, W2t, h2, NNODE, 128, 512, s2, t2, as2, ad2);
  rank_sort_kernel<<<dim3(NNODE / 32, 1), 256, 0, stream>>>(s2, sS2, sI2);
  passA_kernel<<<NCHUNK, 128, 0, stream>>>(h2, sS2, sI2, pP2, pM2, 1);
  passC_kernel<<<NCHUNK, 128, 0, stream>>>(h2, sS2, sI2, pP2, pM2, SS2, PP2, 1);
  attend_kernel<float><<<NNODE, 128, 0, stream>>>(SS2, PP2, sS2, t2, b2, x3, 1);
  // Readout: fused mean + fc (last-block-done)
  mean_fc_kernel<<<128, 256, 0, stream>>>(x3, fcW, fcb, mv, counter, (float*)d_out);
}

// Round 2
// 224.968 us; speedup vs baseline: 1.0911x; 1.0911x over previous
//
#include <hip/hip_runtime.h>
#include <hip/hip_bf16.h>

// FacePartGAT: dense-graph GATConv x2 + mean + fc on MI355X. ALL I/O fp32.
// e[i,j] = leaky_relu(t_i + s_j) => softmax aggregation factorizes after
// sorting sources by s_j (prefix/suffix tables + binary search). Exact.
// Round 13: keep r12 wins (fused s/t GEMM epilogue, one-pass rank sort),
// revert the mean+fc fusion. The agent-scope release/acquire atomics in the
// fused version forced per-block L2 writeback/invalidate across XCDs
// (gfx950 L2s are not coherent) -> 57us idle-tail kernel. Two plain
// dispatches with coalesced partial sums instead: no fences, no atomics.

#define NNODE 4096
#define CDIM 128
#define TW 132           // table width: 128 features + z at col 128
#define NEG 0.2f
#define CHUNK 64
#define NCHUNK 64        // NNODE / CHUNK

typedef __bf16 bf16x8 __attribute__((ext_vector_type(8)));
typedef float f32x4 __attribute__((ext_vector_type(4)));

__device__ __forceinline__ unsigned short f2b(float f) {
  unsigned int u = __float_as_uint(f);
  u += 0x7fffu + ((u >> 16) & 1u);  // RTNE
  return (unsigned short)(u >> 16);
}

// One kernel: [0,3072) convert x -> bf16; [3072,3168) W1 transpose;
// [3168,3184) W2 transpose; [3184,3216) zero s1/t1; [3216,3224) zero s2/t2.
__global__ __launch_bounds__(256) void prep_kernel(const float* __restrict__ x,
                                                   const float* __restrict__ W1,
                                                   const float* __restrict__ W2,
                                                   unsigned short* __restrict__ xb,
                                                   unsigned short* __restrict__ W1t,
                                                   unsigned short* __restrict__ W2t,
                                                   float* __restrict__ zs1,
                                                   float* __restrict__ zs2) {
  __shared__ float tile[64][65];
  int b = blockIdx.x, t = threadIdx.x;
  if (b < 3072) {  // convert x: 4096*768/4 quads
    int i = b * 256 + t;
    float4 v = ((const float4*)x)[i];
    ushort4 o;
    o.x = f2b(v.x); o.y = f2b(v.y); o.z = f2b(v.z); o.w = f2b(v.w);
    ((ushort4*)xb)[i] = o;
    return;
  }
  if (b >= 3184) {  // zero s/t accumulators
    float4 z = {0.f, 0.f, 0.f, 0.f};
    if (b < 3216) {
      ((float4*)zs1)[(b - 3184) * 256 + t] = z;       // s1+t1: 32768 floats
    } else {
      ((float4*)zs2)[(b - 3216) * 256 + t] = z;       // s2+t2: 8192 floats
    }
    return;
  }
  const float* W; unsigned short* Wt; int K, N, n0, k0;
  if (b < 3072 + 96) {  // W1 [768,512] -> W1t [512,768]
    int b2 = b - 3072; W = W1; Wt = W1t; K = 768; N = 512;
    n0 = (b2 & 7) * 64; k0 = (b2 >> 3) * 64;
  } else {              // W2 [512,128] -> W2t [128,512]
    int b3 = b - 3072 - 96; W = W2; Wt = W2t; K = 512; N = 128;
    n0 = (b3 & 1) * 64; k0 = (b3 >> 1) * 64;
  }
  for (int p = 0; p < 16; p++) {
    int e = p * 256 + t;
    int rr = e >> 6, cc = e & 63;
    tile[rr][cc] = W[(size_t)(k0 + rr) * N + n0 + cc];
  }
  __syncthreads();
  for (int p = 0; p < 16; p++) {
    int e = p * 256 + t;
    int rr = e >> 6, cc = e & 63;  // rr: n-dir, cc: k-dir
    Wt[(size_t)(n0 + rr) * K + k0 + cc] = f2b(tile[cc][rr]);
  }
}

// C[M,N] = A[M,K] x Bt[N,K]^T, both bf16 K-contig. BK=32, 256 thr = 4 waves
// (2x2). Register prefetch of tile k+1 between LDS barrier and MFMA.
// Fused epilogue: s[h][n] / t[h][n] partial dot products from acc registers
// (col-reduce over the 16-lane fm group, atomicAdd; one head per block since
// BN=64 and head width 128). Plain device-scope atomicAdd: no fences.
template <int BM, int BN>
__global__ __launch_bounds__(256) void mfma_gemm_bt(const unsigned short* __restrict__ A,
                                                    const unsigned short* __restrict__ Bt,
                                                    float* __restrict__ C,
                                                    int M, int N, int K,
                                                    float* __restrict__ sAcc,
                                                    float* __restrict__ tAcc,
                                                    const float* __restrict__ av_s,
                                                    const float* __restrict__ av_d) {
  __shared__ __align__(16) unsigned short As[BM * 40];
  __shared__ __align__(16) unsigned short Bs[BN * 40];
  constexpr int WM = BM / 2, WN = BN / 2;
  constexpr int FI = WM / 16, FJ = WN / 16;
  constexpr int EA = BM * 32 / 8;
  constexpr int EB = BN * 32 / 8;
  constexpr int NA = (EA + 255) / 256;
  constexpr int NB = (EB + 255) / 256;
  int tid = threadIdx.x;
  int lane = tid & 63, wave = tid >> 6;
  int wm = (wave >> 1) * WM, wn = (wave & 1) * WN;
  int m0 = blockIdx.y * BM, n0 = blockIdx.x * BN;
  int fm = lane & 15, fq = lane >> 4;
  f32x4 acc[FI][FJ] = {};
  uint4 ar[NA], br[NB];
  // preload tile 0
#pragma unroll
  for (int q = 0; q < NA; q++) {
    int e = q * 256 + tid;
    if (e < EA) {
      int r = e >> 2, kk = (e & 3) * 8;
      ar[q] = *(const uint4*)(A + (size_t)(m0 + r) * K + kk);
    }
  }
#pragma unroll
  for (int q = 0; q < NB; q++) {
    int e = q * 256 + tid;
    if (e < EB) {
      int r = e >> 2, kk = (e & 3) * 8;
      br[q] = *(const uint4*)(Bt + (size_t)(n0 + r) * K + kk);
    }
  }
  for (int k0 = 0; k0 < K; k0 += 32) {
    __syncthreads();  // previous iter's ds_reads done before overwrite
#pragma unroll
    for (int q = 0; q < NA; q++) {
      int e = q * 256 + tid;
      if (e < EA) {
        int r = e >> 2, kk = (e & 3) * 8;
        *(uint4*)&As[r * 40 + kk] = ar[q];
      }
    }
#pragma unroll
    for (int q = 0; q < NB; q++) {
      int e = q * 256 + tid;
      if (e < EB) {
        int r = e >> 2, kk = (e & 3) * 8;
        *(uint4*)&Bs[r * 40 + kk] = br[q];
      }
    }
    __syncthreads();
    // prefetch tile k+1 (in flight during ds_read + MFMA below)
    if (k0 + 32 < K) {
#pragma unroll
      for (int q = 0; q < NA; q++) {
        int e = q * 256 + tid;
        if (e < EA) {
          int r = e >> 2, kk = (e & 3) * 8;
          ar[q] = *(const uint4*)(A + (size_t)(m0 + r) * K + k0 + 32 + kk);
        }
      }
#pragma unroll
      for (int q = 0; q < NB; q++) {
        int e = q * 256 + tid;
        if (e < EB) {
          int r = e >> 2, kk = (e & 3) * 8;
          br[q] = *(const uint4*)(Bt + (size_t)(n0 + r) * K + k0 + 32 + kk);
        }
      }
    }
    bf16x8 af[FI], bfr[FJ];
#pragma unroll
    for (int i = 0; i < FI; i++)
      af[i] = *(const bf16x8*)&As[(wm + i * 16 + fm) * 40 + fq * 8];
#pragma unroll
    for (int j = 0; j < FJ; j++)
      bfr[j] = *(const bf16x8*)&Bs[(wn + j * 16 + fm) * 40 + fq * 8];
#pragma unroll
    for (int i = 0; i < FI; i++)
#pragma unroll
      for (int j = 0; j < FJ; j++)
        acc[i][j] = __builtin_amdgcn_mfma_f32_16x16x32_bf16(af[i], bfr[j], acc[i][j], 0, 0, 0);
  }
  // C store
#pragma unroll
  for (int i = 0; i < FI; i++) {
#pragma unroll
    for (int j = 0; j < FJ; j++) {
      int r = m0 + wm + i * 16 + fq * 4;
      int ccol = n0 + wn + j * 16 + fm;
#pragma unroll
      for (int reg = 0; reg < 4; reg++)
        C[(size_t)(r + reg) * N + ccol] = acc[i][j][reg];
    }
  }
  // fused s/t epilogue: row-dot with att vectors. Block spans one head
  // (BN=64, head width 128). av_* indexed by global col (= h*CDIM + c).
  {
    int hh = n0 >> 7;
    float avs[FJ], avd[FJ];
#pragma unroll
    for (int j = 0; j < FJ; j++) {
      int col = n0 + wn + j * 16 + fm;
      avs[j] = av_s[col];
      avd[j] = av_d[col];
    }
#pragma unroll
    for (int i = 0; i < FI; i++) {
#pragma unroll
      for (int reg = 0; reg < 4; reg++) {
        float sv = 0.f, tv = 0.f;
#pragma unroll
        for (int j = 0; j < FJ; j++) {
          sv = fmaf(acc[i][j][reg], avs[j], sv);
          tv = fmaf(acc[i][j][reg], avd[j], tv);
        }
#pragma unroll
        for (int o = 1; o < 16; o <<= 1) {
          sv += __shfl_xor(sv, o, 64);
          tv += __shfl_xor(tv, o, 64);
        }
        if (fm == 0) {
          int row = m0 + wm + i * 16 + fq * 4 + reg;
          atomicAdd(&sAcc[(size_t)hh * NNODE + row], sv);
          atomicAdd(&tAcc[(size_t)hh * NNODE + row], tv);
        }
      }
    }
  }
}

// One-kernel rank sort: all 4096 keys staged in LDS (16 KB). Block = 32
// nodes x 8 scan-parts of 512 keys; partial counts combined in LDS; direct
// scatter of (key, idx) to sorted position. Key reads are wave-uniform per
// 32-lane half -> LDS broadcast, conflict-free.
__global__ __launch_bounds__(256) void rank_sort_kernel(const float* __restrict__ s,
                                                        float* __restrict__ ss,
                                                        int* __restrict__ si) {
  __shared__ __align__(16) float keys[NNODE];
  __shared__ int pc[8][32];
  int hh = blockIdx.y, tid = threadIdx.x;
  const float* sp = s + (size_t)hh * NNODE;
  for (int k = tid; k < NNODE / 4; k += 256)
    ((float4*)keys)[k] = ((const float4*)sp)[k];
  __syncthreads();
  int slot = tid & 31, part = tid >> 5;
  int node = blockIdx.x * 32 + slot;
  float mk = keys[node];
  int cnt = 0;
  int j0 = part * 512;
#pragma unroll 4
  for (int j = j0; j < j0 + 512; j += 4) {
    float4 kv = *(const float4*)&keys[j];
    cnt += (kv.x < mk) || (kv.x == mk && (j + 0) < node);
    cnt += (kv.y < mk) || (kv.y == mk && (j + 1) < node);
    cnt += (kv.z < mk) || (kv.z == mk && (j + 2) < node);
    cnt += (kv.w < mk) || (kv.w == mk && (j + 3) < node);
  }
  pc[part][slot] = cnt;
  __syncthreads();
  if (tid < 32) {
    int rank = 0;
#pragma unroll
    for (int p = 0; p < 8; p++) rank += pc[p][tid];
    int n2 = blockIdx.x * 32 + tid;
    ss[(size_t)hh * NNODE + rank] = keys[n2];
    si[(size_t)hh * NNODE + rank] = n2;
  }
}

// Pass A: per-chunk partial sums of e^{s}*h (P) and e^{0.2s}*h (M); z at 128.
__global__ __launch_bounds__(128) void passA_kernel(const float* __restrict__ h,
                                                    const float* __restrict__ ss,
                                                    const int* __restrict__ si,
                                                    float* __restrict__ partP,
                                                    float* __restrict__ partM, int H) {
  __shared__ float eP[CHUNK], eM[CHUNK];
  __shared__ int ids[CHUNK];
  int b = blockIdx.x, hh = b / NCHUNK, ci = b % NCHUNK;
  int c = threadIdx.x;
  int HC = H * CDIM;
  int base = ci * CHUNK;
  if (c < CHUNK) {
    float sv = ss[(size_t)hh * NNODE + base + c];
    ids[c] = si[(size_t)hh * NNODE + base + c];
    eP[c] = expf(sv);
    eM[c] = expf(NEG * sv);
  }
  __syncthreads();
  float sp = 0.f, sm = 0.f;
  for (int kb = 0; kb < CHUNK; kb += 8) {
    float v[8];
#pragma unroll
    for (int j = 0; j < 8; j++)
      v[j] = h[(size_t)ids[kb + j] * HC + hh * CDIM + c];
#pragma unroll
    for (int j = 0; j < 8; j++) {
      sp = fmaf(eP[kb + j], v[j], sp);
      sm = fmaf(eM[kb + j], v[j], sm);
    }
  }
  size_t o = ((size_t)hh * NCHUNK + ci) * TW;
  partP[o + c] = sp;
  partM[o + c] = sm;
  if (c == 0) {
    float zp = 0.f, zm = 0.f;
#pragma unroll
    for (int k = 0; k < CHUNK; k++) { zp += eP[k]; zm += eM[k]; }
    partP[o + 128] = zp;
    partM[o + 128] = zm;
  }
}

// Pass C with fused BATCHED carry combine (16 independent loads in flight).
// LDS-staged gather + dual scan, z at col 128.
__global__ __launch_bounds__(128) void passC_kernel(const float* __restrict__ h,
                                                    const float* __restrict__ ss,
                                                    const int* __restrict__ si,
                                                    const float* __restrict__ partP,
                                                    const float* __restrict__ partM,
                                                    float* __restrict__ SS,
                                                    float* __restrict__ PP, int H) {
  __shared__ float hrow[CHUNK][CDIM];  // 32 KB
  __shared__ float eP[CHUNK], eM[CHUNK];
  __shared__ int ids[CHUNK];
  int b = blockIdx.x, hh = b / NCHUNK, ci = b % NCHUNK;
  int c = threadIdx.x;
  int HC = H * CDIM;
  int base = ci * CHUNK;
  size_t hb = (size_t)hh * (NNODE + 1);
  if (c < CHUNK) {
    float sv = ss[(size_t)hh * NNODE + base + c];
    ids[c] = si[(size_t)hh * NNODE + base + c];
    eP[c] = expf(sv);
    eM[c] = expf(NEG * sv);
  }
  __syncthreads();
  // carry combine: feature columns (all threads), 16 loads in flight
  float cm = 0.f, cp = 0.f;
  for (int g0 = 0; g0 < NCHUNK; g0 += 16) {
    float vm[16], vp[16];
#pragma unroll
    for (int j = 0; j < 16; j++) {
      size_t o = ((size_t)hh * NCHUNK + g0 + j) * TW + c;
      vm[j] = partM[o];
      vp[j] = partP[o];
    }
#pragma unroll
    for (int j = 0; j < 16; j++) {
      if (g0 + j < ci) cm += vm[j];
      if (g0 + j > ci) cp += vp[j];
    }
  }
  // z carries (thread 0 only)
  float zcm = 0.f, zcp = 0.f;
  if (c == 0) {
    for (int g0 = 0; g0 < NCHUNK; g0 += 16) {
      float vm[16], vp[16];
#pragma unroll
      for (int j = 0; j < 16; j++) {
        size_t o = ((size_t)hh * NCHUNK + g0 + j) * TW + 128;
        vm[j] = partM[o];
        vp[j] = partP[o];
      }
#pragma unroll
      for (int j = 0; j < 16; j++) {
        if (g0 + j < ci) zcm += vm[j];
        if (g0 + j > ci) zcp += vp[j];
      }
    }
  }
  // gather h rows once into LDS (batched, per-thread column)
  for (int kb = 0; kb < CHUNK; kb += 8) {
    float v[8];
#pragma unroll
    for (int j = 0; j < 8; j++)
      v[j] = h[(size_t)ids[kb + j] * HC + hh * CDIM + c];
#pragma unroll
    for (int j = 0; j < 8; j++) hrow[kb + j][c] = v[j];
  }
  float runm = cm, runzm = zcm;
#pragma unroll 8
  for (int k = 0; k < CHUNK; k++) {
    size_t row = (hb + base + k) * TW;
    PP[row + c] = runm;
    if (c == 0) PP[row + 128] = runzm;
    runm = fmaf(eM[k], hrow[k][c], runm);
    runzm += eM[k];
  }
  if (ci == NCHUNK - 1) {
    size_t row = (hb + NNODE) * TW;
    PP[row + c] = runm;
    if (c == 0) PP[row + 128] = runzm;
  }
  float runp = cp, runzp = zcp;
#pragma unroll 8
  for (int k = CHUNK - 1; k >= 0; k--) {
    runp = fmaf(eP[k], hrow[k][c], runp);
    runzp += eP[k];
    size_t row = (hb + base + k) * TW;
    SS[row + c] = runp;
    if (c == 0) SS[row + 128] = runzp;
  }
  if (ci == NCHUNK - 1) {
    size_t row = (hb + NNODE) * TW;
    SS[row + c] = 0.f;
    if (c == 0) SS[row + 128] = 0.f;
  }
}

// Per (dest, head): binary search split point, combine tables, +bias, ELU.
template <typename OUT>
__global__ __launch_bounds__(128) void attend_kernel(const float* __restrict__ SS,
                                                     const float* __restrict__ PP,
                                                     const float* __restrict__ ss,
                                                     const float* __restrict__ tt,
                                                     const float* __restrict__ bias,
                                                     OUT* __restrict__ out, int H) {
  int b = blockIdx.x;
  int n = b / H, hh = b % H;
  int c = threadIdx.x;
  float tv = tt[(size_t)hh * NNODE + n];
  const float* sp = ss + (size_t)hh * NNODE;
  float thr = -tv;
  int lo = 0, hi = NNODE;
  while (lo < hi) { int mid = (lo + hi) >> 1; if (sp[mid] < thr) lo = mid + 1; else hi = mid; }
  size_t hb = (size_t)hh * (NNODE + 1);
  float wp = expf(tv), wm = expf(NEG * tv);
  float num = wp * SS[(hb + lo) * TW + c] + wm * PP[(hb + lo) * TW + c];
  float Z = wp * SS[(hb + lo) * TW + 128] + wm * PP[(hb + lo) * TW + 128];
  float o = num / Z + bias[hh * CDIM + c];
  float r = (o > 0.f) ? o : (expf(o) - 1.f);
  if constexpr (sizeof(OUT) == 2)
    out[(size_t)n * (H * CDIM) + hh * CDIM + c] = f2b(r);
  else
    out[(size_t)n * (H * CDIM) + hh * CDIM + c] = r;
}

// Coalesced column partial sums: block b sums rows [b*64, b*64+64) into
// part[b][128]. float4 loads, LDS tree over row-groups. No atomics.
__global__ __launch_bounds__(256) void mean_part_kernel(const float* __restrict__ x,
                                                        float* __restrict__ part) {
  __shared__ float4 red[256];
  int b = blockIdx.x, tid = threadIdx.x;
  int q = tid & 31, r0 = tid >> 5;  // q: col quad (4 cols), r0: row group
  const float4* xp = (const float4*)x;
  float4 s = {0.f, 0.f, 0.f, 0.f};
  int base = b * 64;
  for (int r = r0; r < 64; r += 8) {
    float4 v = xp[(size_t)(base + r) * 32 + q];
    s.x += v.x; s.y += v.y; s.z += v.z; s.w += v.w;
  }
  red[tid] = s; __syncthreads();
  for (int off = 4; off > 0; off >>= 1) {
    if (r0 < off) {
      float4 o = red[tid + off * 32];
      red[tid].x += o.x; red[tid].y += o.y; red[tid].z += o.z; red[tid].w += o.w;
    }
    __syncthreads();
  }
  if (tid < 32) ((float4*)part)[b * 32 + tid] = red[tid];
}

// Reduce the 64x128 partials (redundantly per block, trivial) then GEMV.
__global__ __launch_bounds__(256) void fc_kernel(const float* __restrict__ part,
                                                 const float* __restrict__ fcW,
                                                 const float* __restrict__ fcb,
                                                 float* __restrict__ out) {
  __shared__ float tmp[256];
  __shared__ float m[CDIM];
  int tid = threadIdx.x;
  int c = tid & 127, half = tid >> 7;
  float a = 0.f;
  for (int g = half; g < 64; g += 2) a += part[g * CDIM + c];
  tmp[tid] = a; __syncthreads();
  if (tid < 128) m[tid] = (tmp[tid] + tmp[tid + 128]) * (1.f / NNODE);
  __syncthreads();
  int d = blockIdx.x * 256 + tid;  // 768 total
  float acc = fcb[d];
#pragma unroll 4
  for (int c2 = 0; c2 < CDIM; c2++) acc = fmaf(m[c2], fcW[c2 * 768 + d], acc);
  out[d] = acc;
}

extern "C" void kernel_launch(void* const* d_in, const int* in_sizes, int n_in,
                              void* d_out, int out_size, void* d_ws, size_t ws_size,
                              hipStream_t stream) {
  const float* x   = (const float*)d_in[0];
  const float* W1  = (const float*)d_in[1];
  const float* as1 = (const float*)d_in[2];
  const float* ad1 = (const float*)d_in[3];
  const float* b1  = (const float*)d_in[4];
  const float* W2  = (const float*)d_in[5];
  const float* as2 = (const float*)d_in[6];
  const float* ad2 = (const float*)d_in[7];
  const float* b2  = (const float*)d_in[8];
  const float* fcW = (const float*)d_in[9];
  const float* fcb = (const float*)d_in[10];

  float* ws = (float*)d_ws;
  size_t off = 0;
  auto alloc = [&](size_t nfloats) { float* p = ws + off; off += nfloats; return p; };

  float* h1  = alloc((size_t)NNODE * 512);
  float* x2f = alloc((size_t)NNODE * 256 + 64 + 16384);  // x2b bf16 + W2t bf16
  float* h2  = alloc((size_t)NNODE * 128);
  float* x3  = alloc((size_t)NNODE * 128);
  float* s1  = alloc((size_t)4 * NNODE);
  float* t1  = alloc((size_t)4 * NNODE);
  float* sS1 = alloc((size_t)4 * NNODE);
  int*   sI1 = (int*)alloc((size_t)4 * NNODE);
  float* SS1 = alloc((size_t)4 * (NNODE + 1) * TW);
  float* PP1 = alloc((size_t)4 * (NNODE + 1) * TW);
  float* pP1 = alloc((size_t)4 * NCHUNK * TW);
  float* pM1 = alloc((size_t)4 * NCHUNK * TW);
  float* s2  = alloc(NNODE);
  float* t2  = alloc(NNODE);
  float* sS2 = alloc(NNODE);
  int*   sI2 = (int*)alloc(NNODE);
  float* SS2 = alloc((size_t)(NNODE + 1) * TW);
  float* PP2 = alloc((size_t)(NNODE + 1) * TW);
  float* pP2 = alloc((size_t)NCHUNK * TW);
  float* pM2 = alloc((size_t)NCHUNK * TW);
  float* mpart = alloc((size_t)64 * CDIM);  // mean partial sums

  // bf16 staging aliased into PP1/SS1 (first written by passC1, strictly after
  // gemm1 last reads them — stream ordered).
  unsigned short* xb  = (unsigned short*)PP1;  // 4096x768 bf16 = 6.3 MB (< 8.65 MB)
  unsigned short* W1t = (unsigned short*)SS1;  // 512x768 bf16
  unsigned short* x2b = (unsigned short*)x2f;                       // 4096x512 bf16
  unsigned short* W2t = (unsigned short*)(x2f + NNODE * 256 + 64);  // 128x512 bf16

  // Prep: convert x + transpose/cast W1, W2 + zero s/t accumulators
  prep_kernel<<<3224, 256, 0, stream>>>(x, W1, W2, xb, W1t, W2t, s1, s2);
  // Layer 1 (64x64 tiles -> 512 blocks; fused s/t epilogue)
  mfma_gemm_bt<64, 64><<<dim3(512 / 64, NNODE / 64), 256, 0, stream>>>(
      xb, W1t, h1, NNODE, 512, 768, s1, t1, as1, ad1);
  rank_sort_kernel<<<dim3(NNODE / 32, 4), 256, 0, stream>>>(s1, sS1, sI1);
  passA_kernel<<<4 * NCHUNK, 128, 0, stream>>>(h1, sS1, sI1, pP1, pM1, 4);
  passC_kernel<<<4 * NCHUNK, 128, 0, stream>>>(h1, sS1, sI1, pP1, pM1, SS1, PP1, 4);
  attend_kernel<unsigned short><<<NNODE * 4, 128, 0, stream>>>(SS1, PP1, sS1, t1, b1, x2b, 4);
  // Layer 2 (32x64 tiles -> 256 blocks; fused s/t epilogue)
  mfma_gemm_bt<32, 64><<<dim3(128 / 64, NNODE / 32), 256, 0, stream>>>(
      x2b, W2t, h2, NNODE, 128, 512, s2, t2, as2, ad2);
  rank_sort_kernel<<<dim3(NNODE / 32, 1), 256, 0, stream>>>(s2, sS2, sI2);
  passA_kernel<<<NCHUNK, 128, 0, stream>>>(h2, sS2, sI2, pP2, pM2, 1);
  passC_kernel<<<NCHUNK, 128, 0, stream>>>(h2, sS2, sI2, pP2, pM2, SS2, PP2, 1);
  attend_kernel<float><<<NNODE, 128, 0, stream>>>(SS2, PP2, sS2, t2, b2, x3, 1);
  // Readout: coalesced mean partials + fc
  mean_part_kernel<<<64, 256, 0, stream>>>(x3, mpart);
  fc_kernel<<<3, 256, 0, stream>>>(mpart, fcW, fcb, (float*)d_out);
}

// Round 3
// 209.636 us; speedup vs baseline: 1.1709x; 1.0731x over previous
//
#include <hip/hip_runtime.h>
#include <hip/hip_bf16.h>

// FacePartGAT: dense-graph GATConv x2 + mean + fc on MI355X. ALL I/O fp32.
// e[i,j] = leaky_relu(t_i + s_j) => softmax aggregation factorizes after
// sorting sources by s_j (prefix/suffix tables + binary search). Exact.
// Round 14: latency attack on the scan/attend pipeline.
//  - CHUNK 64->32 (NCHUNK 128): passA/passC occupancy 1->2 blocks/CU,
//    serial scans halved.
//  - new passB: per-head prefix/suffix scan of chunk partials; passC's
//    per-block O(NCHUNK) carry loops -> 2 coalesced row loads.
//  - rank_sort also counts lo = #{j: s_j < -t_i} (strict <, identical to
//    the old binary search) while keys are in LDS; attend loses its
//    12-step dependent search chain.

#define NNODE 4096
#define CDIM 128
#define TW 132           // table width: 128 features + z at col 128
#define NEG 0.2f
#define CHUNK 32
#define NCHUNK 128       // NNODE / CHUNK

typedef __bf16 bf16x8 __attribute__((ext_vector_type(8)));
typedef float f32x4 __attribute__((ext_vector_type(4)));

__device__ __forceinline__ unsigned short f2b(float f) {
  unsigned int u = __float_as_uint(f);
  u += 0x7fffu + ((u >> 16) & 1u);  // RTNE
  return (unsigned short)(u >> 16);
}

// One kernel: [0,3072) convert x -> bf16; [3072,3168) W1 transpose;
// [3168,3184) W2 transpose; [3184,3216) zero s1/t1; [3216,3224) zero s2/t2.
__global__ __launch_bounds__(256) void prep_kernel(const float* __restrict__ x,
                                                   const float* __restrict__ W1,
                                                   const float* __restrict__ W2,
                                                   unsigned short* __restrict__ xb,
                                                   unsigned short* __restrict__ W1t,
                                                   unsigned short* __restrict__ W2t,
                                                   float* __restrict__ zs1,
                                                   float* __restrict__ zs2) {
  __shared__ float tile[64][65];
  int b = blockIdx.x, t = threadIdx.x;
  if (b < 3072) {  // convert x: 4096*768/4 quads
    int i = b * 256 + t;
    float4 v = ((const float4*)x)[i];
    ushort4 o;
    o.x = f2b(v.x); o.y = f2b(v.y); o.z = f2b(v.z); o.w = f2b(v.w);
    ((ushort4*)xb)[i] = o;
    return;
  }
  if (b >= 3184) {  // zero s/t accumulators
    float4 z = {0.f, 0.f, 0.f, 0.f};
    if (b < 3216) {
      ((float4*)zs1)[(b - 3184) * 256 + t] = z;       // s1+t1: 32768 floats
    } else {
      ((float4*)zs2)[(b - 3216) * 256 + t] = z;       // s2+t2: 8192 floats
    }
    return;
  }
  const float* W; unsigned short* Wt; int K, N, n0, k0;
  if (b < 3072 + 96) {  // W1 [768,512] -> W1t [512,768]
    int b2 = b - 3072; W = W1; Wt = W1t; K = 768; N = 512;
    n0 = (b2 & 7) * 64; k0 = (b2 >> 3) * 64;
  } else {              // W2 [512,128] -> W2t [128,512]
    int b3 = b - 3072 - 96; W = W2; Wt = W2t; K = 512; N = 128;
    n0 = (b3 & 1) * 64; k0 = (b3 >> 1) * 64;
  }
  for (int p = 0; p < 16; p++) {
    int e = p * 256 + t;
    int rr = e >> 6, cc = e & 63;
    tile[rr][cc] = W[(size_t)(k0 + rr) * N + n0 + cc];
  }
  __syncthreads();
  for (int p = 0; p < 16; p++) {
    int e = p * 256 + t;
    int rr = e >> 6, cc = e & 63;  // rr: n-dir, cc: k-dir
    Wt[(size_t)(n0 + rr) * K + k0 + cc] = f2b(tile[cc][rr]);
  }
}

// C[M,N] = A[M,K] x Bt[N,K]^T, both bf16 K-contig. BK=32, 256 thr = 4 waves
// (2x2). Register prefetch of tile k+1 between LDS barrier and MFMA.
// Fused epilogue: s[h][n] / t[h][n] partial dot products from acc registers
// (col-reduce over the 16-lane fm group, atomicAdd; one head per block since
// BN=64 and head width 128). Plain device-scope atomicAdd: no fences.
template <int BM, int BN>
__global__ __launch_bounds__(256) void mfma_gemm_bt(const unsigned short* __restrict__ A,
                                                    const unsigned short* __restrict__ Bt,
                                                    float* __restrict__ C,
                                                    int M, int N, int K,
                                                    float* __restrict__ sAcc,
                                                    float* __restrict__ tAcc,
                                                    const float* __restrict__ av_s,
                                                    const float* __restrict__ av_d) {
  __shared__ __align__(16) unsigned short As[BM * 40];
  __shared__ __align__(16) unsigned short Bs[BN * 40];
  constexpr int WM = BM / 2, WN = BN / 2;
  constexpr int FI = WM / 16, FJ = WN / 16;
  constexpr int EA = BM * 32 / 8;
  constexpr int EB = BN * 32 / 8;
  constexpr int NA = (EA + 255) / 256;
  constexpr int NB = (EB + 255) / 256;
  int tid = threadIdx.x;
  int lane = tid & 63, wave = tid >> 6;
  int wm = (wave >> 1) * WM, wn = (wave & 1) * WN;
  int m0 = blockIdx.y * BM, n0 = blockIdx.x * BN;
  int fm = lane & 15, fq = lane >> 4;
  f32x4 acc[FI][FJ] = {};
  uint4 ar[NA], br[NB];
  // preload tile 0
#pragma unroll
  for (int q = 0; q < NA; q++) {
    int e = q * 256 + tid;
    if (e < EA) {
      int r = e >> 2, kk = (e & 3) * 8;
      ar[q] = *(const uint4*)(A + (size_t)(m0 + r) * K + kk);
    }
  }
#pragma unroll
  for (int q = 0; q < NB; q++) {
    int e = q * 256 + tid;
    if (e < EB) {
      int r = e >> 2, kk = (e & 3) * 8;
      br[q] = *(const uint4*)(Bt + (size_t)(n0 + r) * K + kk);
    }
  }
  for (int k0 = 0; k0 < K; k0 += 32) {
    __syncthreads();  // previous iter's ds_reads done before overwrite
#pragma unroll
    for (int q = 0; q < NA; q++) {
      int e = q * 256 + tid;
      if (e < EA) {
        int r = e >> 2, kk = (e & 3) * 8;
        *(uint4*)&As[r * 40 + kk] = ar[q];
      }
    }
#pragma unroll
    for (int q = 0; q < NB; q++) {
      int e = q * 256 + tid;
      if (e < EB) {
        int r = e >> 2, kk = (e & 3) * 8;
        *(uint4*)&Bs[r * 40 + kk] = br[q];
      }
    }
    __syncthreads();
    // prefetch tile k+1 (in flight during ds_read + MFMA below)
    if (k0 + 32 < K) {
#pragma unroll
      for (int q = 0; q < NA; q++) {
        int e = q * 256 + tid;
        if (e < EA) {
          int r = e >> 2, kk = (e & 3) * 8;
          ar[q] = *(const uint4*)(A + (size_t)(m0 + r) * K + k0 + 32 + kk);
        }
      }
#pragma unroll
      for (int q = 0; q < NB; q++) {
        int e = q * 256 + tid;
        if (e < EB) {
          int r = e >> 2, kk = (e & 3) * 8;
          br[q] = *(const uint4*)(Bt + (size_t)(n0 + r) * K + k0 + 32 + kk);
        }
      }
    }
    bf16x8 af[FI], bfr[FJ];
#pragma unroll
    for (int i = 0; i < FI; i++)
      af[i] = *(const bf16x8*)&As[(wm + i * 16 + fm) * 40 + fq * 8];
#pragma unroll
    for (int j = 0; j < FJ; j++)
      bfr[j] = *(const bf16x8*)&Bs[(wn + j * 16 + fm) * 40 + fq * 8];
#pragma unroll
    for (int i = 0; i < FI; i++)
#pragma unroll
      for (int j = 0; j < FJ; j++)
        acc[i][j] = __builtin_amdgcn_mfma_f32_16x16x32_bf16(af[i], bfr[j], acc[i][j], 0, 0, 0);
  }
  // C store
#pragma unroll
  for (int i = 0; i < FI; i++) {
#pragma unroll
    for (int j = 0; j < FJ; j++) {
      int r = m0 + wm + i * 16 + fq * 4;
      int ccol = n0 + wn + j * 16 + fm;
#pragma unroll
      for (int reg = 0; reg < 4; reg++)
        C[(size_t)(r + reg) * N + ccol] = acc[i][j][reg];
    }
  }
  // fused s/t epilogue: row-dot with att vectors. Block spans one head
  // (BN=64, head width 128). av_* indexed by global col (= h*CDIM + c).
  {
    int hh = n0 >> 7;
    float avs[FJ], avd[FJ];
#pragma unroll
    for (int j = 0; j < FJ; j++) {
      int col = n0 + wn + j * 16 + fm;
      avs[j] = av_s[col];
      avd[j] = av_d[col];
    }
#pragma unroll
    for (int i = 0; i < FI; i++) {
#pragma unroll
      for (int reg = 0; reg < 4; reg++) {
        float sv = 0.f, tv = 0.f;
#pragma unroll
        for (int j = 0; j < FJ; j++) {
          sv = fmaf(acc[i][j][reg], avs[j], sv);
          tv = fmaf(acc[i][j][reg], avd[j], tv);
        }
#pragma unroll
        for (int o = 1; o < 16; o <<= 1) {
          sv += __shfl_xor(sv, o, 64);
          tv += __shfl_xor(tv, o, 64);
        }
        if (fm == 0) {
          int row = m0 + wm + i * 16 + fq * 4 + reg;
          atomicAdd(&sAcc[(size_t)hh * NNODE + row], sv);
          atomicAdd(&tAcc[(size_t)hh * NNODE + row], tv);
        }
      }
    }
  }
}

// One-kernel rank sort + query split precompute. All 4096 keys in LDS
// (16 KB). Block = 32 nodes x 8 scan-parts of 512 keys; partial counts
// combined in LDS; direct scatter of (key, idx) to sorted position.
// ALSO counts lo[n] = #{j : s_j < -t_n} (strict <), which is bit-identical
// to lower_bound(sorted_s, -t_n) -- removes attend's binary search.
__global__ __launch_bounds__(256) void rank_sort_kernel(const float* __restrict__ s,
                                                        const float* __restrict__ t,
                                                        float* __restrict__ ss,
                                                        int* __restrict__ si,
                                                        int* __restrict__ qlo) {
  __shared__ __align__(16) float keys[NNODE];
  __shared__ int pc[8][32], qc[8][32];
  int hh = blockIdx.y, tid = threadIdx.x;
  const float* sp = s + (size_t)hh * NNODE;
  for (int k = tid; k < NNODE / 4; k += 256)
    ((float4*)keys)[k] = ((const float4*)sp)[k];
  __syncthreads();
  int slot = tid & 31, part = tid >> 5;
  int node = blockIdx.x * 32 + slot;
  float mk = keys[node];
  float qk = -t[(size_t)hh * NNODE + node];
  int cnt = 0, cq = 0;
  int j0 = part * 512;
#pragma unroll 4
  for (int j = j0; j < j0 + 512; j += 4) {
    float4 kv = *(const float4*)&keys[j];
    cnt += (kv.x < mk) || (kv.x == mk && (j + 0) < node);
    cnt += (kv.y < mk) || (kv.y == mk && (j + 1) < node);
    cnt += (kv.z < mk) || (kv.z == mk && (j + 2) < node);
    cnt += (kv.w < mk) || (kv.w == mk && (j + 3) < node);
    cq += (kv.x < qk) + (kv.y < qk) + (kv.z < qk) + (kv.w < qk);
  }
  pc[part][slot] = cnt;
  qc[part][slot] = cq;
  __syncthreads();
  if (tid < 32) {
    int rank = 0;
#pragma unroll
    for (int p = 0; p < 8; p++) rank += pc[p][tid];
    int n2 = blockIdx.x * 32 + tid;
    ss[(size_t)hh * NNODE + rank] = keys[n2];
    si[(size_t)hh * NNODE + rank] = n2;
  } else if (tid < 64) {
    int sl = tid - 32;
    int lo = 0;
#pragma unroll
    for (int p = 0; p < 8; p++) lo += qc[p][sl];
    qlo[(size_t)hh * NNODE + blockIdx.x * 32 + sl] = lo;
  }
}

// Pass A: per-chunk partial sums of e^{s}*h (P) and e^{0.2s}*h (M); z at 128.
__global__ __launch_bounds__(128) void passA_kernel(const float* __restrict__ h,
                                                    const float* __restrict__ ss,
                                                    const int* __restrict__ si,
                                                    float* __restrict__ partP,
                                                    float* __restrict__ partM, int H) {
  __shared__ float eP[CHUNK], eM[CHUNK];
  __shared__ int ids[CHUNK];
  int b = blockIdx.x, hh = b / NCHUNK, ci = b % NCHUNK;
  int c = threadIdx.x;
  int HC = H * CDIM;
  int base = ci * CHUNK;
  if (c < CHUNK) {
    float sv = ss[(size_t)hh * NNODE + base + c];
    ids[c] = si[(size_t)hh * NNODE + base + c];
    eP[c] = expf(sv);
    eM[c] = expf(NEG * sv);
  }
  __syncthreads();
  float sp = 0.f, sm = 0.f;
  for (int kb = 0; kb < CHUNK; kb += 8) {
    float v[8];
#pragma unroll
    for (int j = 0; j < 8; j++)
      v[j] = h[(size_t)ids[kb + j] * HC + hh * CDIM + c];
#pragma unroll
    for (int j = 0; j < 8; j++) {
      sp = fmaf(eP[kb + j], v[j], sp);
      sm = fmaf(eM[kb + j], v[j], sm);
    }
  }
  size_t o = ((size_t)hh * NCHUNK + ci) * TW;
  partP[o + c] = sp;
  partM[o + c] = sm;
  if (c == 0) {
    float zp = 0.f, zm = 0.f;
#pragma unroll
    for (int k = 0; k < CHUNK; k++) { zp += eP[k]; zm += eM[k]; }
    partP[o + 128] = zp;
    partM[o + 128] = zm;
  }
}

// Pass B: per-head exclusive prefix scan of partM (forward) and exclusive
// suffix scan of partP (backward) over the NCHUNK chunk partials, incl. z.
// Removes passC's per-block O(NCHUNK) carry loops. 2 blocks/head.
__global__ __launch_bounds__(192) void passB_kernel(const float* __restrict__ partP,
                                                    const float* __restrict__ partM,
                                                    float* __restrict__ sufP,
                                                    float* __restrict__ prefM) {
  int hh = blockIdx.y, dir = blockIdx.x;
  int c = threadIdx.x;
  if (c > 128) return;  // 129 cols: 128 features + z
  size_t base = (size_t)hh * NCHUNK * TW;
  if (dir == 0) {  // forward exclusive prefix of partM
    float run = 0.f;
    for (int g0 = 0; g0 < NCHUNK; g0 += 8) {
      float v[8];
#pragma unroll
      for (int j = 0; j < 8; j++) v[j] = partM[base + (size_t)(g0 + j) * TW + c];
#pragma unroll
      for (int j = 0; j < 8; j++) {
        prefM[base + (size_t)(g0 + j) * TW + c] = run;
        run += v[j];
      }
    }
  } else {  // backward exclusive suffix of partP
    float run = 0.f;
    for (int g0 = NCHUNK - 8; g0 >= 0; g0 -= 8) {
      float v[8];
#pragma unroll
      for (int j = 7; j >= 0; j--) v[j] = partP[base + (size_t)(g0 + j) * TW + c];
#pragma unroll
      for (int j = 7; j >= 0; j--) {
        sufP[base + (size_t)(g0 + j) * TW + c] = run;
        run += v[j];
      }
    }
  }
}

// Pass C: carries from passB (2 coalesced row loads), LDS-staged gather,
// dual scan writing prefix/suffix tables, z at col 128.
__global__ __launch_bounds__(128) void passC_kernel(const float* __restrict__ h,
                                                    const float* __restrict__ ss,
                                                    const int* __restrict__ si,
                                                    const float* __restrict__ sufP,
                                                    const float* __restrict__ prefM,
                                                    float* __restrict__ SS,
                                                    float* __restrict__ PP, int H) {
  __shared__ float hrow[CHUNK][CDIM];  // 16 KB
  __shared__ float eP[CHUNK], eM[CHUNK];
  __shared__ int ids[CHUNK];
  int b = blockIdx.x, hh = b / NCHUNK, ci = b % NCHUNK;
  int c = threadIdx.x;
  int HC = H * CDIM;
  int base = ci * CHUNK;
  size_t hb = (size_t)hh * (NNODE + 1);
  if (c < CHUNK) {
    float sv = ss[(size_t)hh * NNODE + base + c];
    ids[c] = si[(size_t)hh * NNODE + base + c];
    eP[c] = expf(sv);
    eM[c] = expf(NEG * sv);
  }
  __syncthreads();
  size_t co = ((size_t)hh * NCHUNK + ci) * TW;
  float cm = prefM[co + c];
  float cp = sufP[co + c];
  float zcm = 0.f, zcp = 0.f;
  if (c == 0) { zcm = prefM[co + 128]; zcp = sufP[co + 128]; }
  // gather h rows once into LDS (batched, per-thread column)
  for (int kb = 0; kb < CHUNK; kb += 8) {
    float v[8];
#pragma unroll
    for (int j = 0; j < 8; j++)
      v[j] = h[(size_t)ids[kb + j] * HC + hh * CDIM + c];
#pragma unroll
    for (int j = 0; j < 8; j++) hrow[kb + j][c] = v[j];
  }
  float runm = cm, runzm = zcm;
#pragma unroll 8
  for (int k = 0; k < CHUNK; k++) {
    size_t row = (hb + base + k) * TW;
    PP[row + c] = runm;
    if (c == 0) PP[row + 128] = runzm;
    runm = fmaf(eM[k], hrow[k][c], runm);
    runzm += eM[k];
  }
  if (ci == NCHUNK - 1) {
    size_t row = (hb + NNODE) * TW;
    PP[row + c] = runm;
    if (c == 0) PP[row + 128] = runzm;
  }
  float runp = cp, runzp = zcp;
#pragma unroll 8
  for (int k = CHUNK - 1; k >= 0; k--) {
    runp = fmaf(eP[k], hrow[k][c], runp);
    runzp += eP[k];
    size_t row = (hb + base + k) * TW;
    SS[row + c] = runp;
    if (c == 0) SS[row + 128] = runzp;
  }
  if (ci == NCHUNK - 1) {
    size_t row = (hb + NNODE) * TW;
    SS[row + c] = 0.f;
    if (c == 0) SS[row + 128] = 0.f;
  }
}

// Per (dest, head): split point precomputed (qlo), combine tables, +bias, ELU.
template <typename OUT>
__global__ __launch_bounds__(128) void attend_kernel(const float* __restrict__ SS,
                                                     const float* __restrict__ PP,
                                                     const int* __restrict__ qlo,
                                                     const float* __restrict__ tt,
                                                     const float* __restrict__ bias,
                                                     OUT* __restrict__ out, int H) {
  int b = blockIdx.x;
  int n = b / H, hh = b % H;
  int c = threadIdx.x;
  float tv = tt[(size_t)hh * NNODE + n];
  int lo = qlo[(size_t)hh * NNODE + n];
  size_t hb = (size_t)hh * (NNODE + 1);
  float wp = expf(tv), wm = expf(NEG * tv);
  float num = wp * SS[(hb + lo) * TW + c] + wm * PP[(hb + lo) * TW + c];
  float Z = wp * SS[(hb + lo) * TW + 128] + wm * PP[(hb + lo) * TW + 128];
  float o = num / Z + bias[hh * CDIM + c];
  float r = (o > 0.f) ? o : (expf(o) - 1.f);
  if constexpr (sizeof(OUT) == 2)
    out[(size_t)n * (H * CDIM) + hh * CDIM + c] = f2b(r);
  else
    out[(size_t)n * (H * CDIM) + hh * CDIM + c] = r;
}

// Coalesced column partial sums: block b sums rows [b*64, b*64+64) into
// part[b][128]. float4 loads, LDS tree over row-groups. No atomics.
__global__ __launch_bounds__(256) void mean_part_kernel(const float* __restrict__ x,
                                                        float* __restrict__ part) {
  __shared__ float4 red[256];
  int b = blockIdx.x, tid = threadIdx.x;
  int q = tid & 31, r0 = tid >> 5;  // q: col quad (4 cols), r0: row group
  const float4* xp = (const float4*)x;
  float4 s = {0.f, 0.f, 0.f, 0.f};
  int base = b * 64;
  for (int r = r0; r < 64; r += 8) {
    float4 v = xp[(size_t)(base + r) * 32 + q];
    s.x += v.x; s.y += v.y; s.z += v.z; s.w += v.w;
  }
  red[tid] = s; __syncthreads();
  for (int off = 4; off > 0; off >>= 1) {
    if (r0 < off) {
      float4 o = red[tid + off * 32];
      red[tid].x += o.x; red[tid].y += o.y; red[tid].z += o.z; red[tid].w += o.w;
    }
    __syncthreads();
  }
  if (tid < 32) ((float4*)part)[b * 32 + tid] = red[tid];
}

// Reduce the 64x128 partials (redundantly per block, trivial) then GEMV.
__global__ __launch_bounds__(256) void fc_kernel(const float* __restrict__ part,
                                                 const float* __restrict__ fcW,
                                                 const float* __restrict__ fcb,
                                                 float* __restrict__ out) {
  __shared__ float tmp[256];
  __shared__ float m[CDIM];
  int tid = threadIdx.x;
  int c = tid & 127, half = tid >> 7;
  float a = 0.f;
  for (int g = half; g < 64; g += 2) a += part[g * CDIM + c];
  tmp[tid] = a; __syncthreads();
  if (tid < 128) m[tid] = (tmp[tid] + tmp[tid + 128]) * (1.f / NNODE);
  __syncthreads();
  int d = blockIdx.x * 256 + tid;  // 768 total
  float acc = fcb[d];
#pragma unroll 4
  for (int c2 = 0; c2 < CDIM; c2++) acc = fmaf(m[c2], fcW[c2 * 768 + d], acc);
  out[d] = acc;
}

extern "C" void kernel_launch(void* const* d_in, const int* in_sizes, int n_in,
                              void* d_out, int out_size, void* d_ws, size_t ws_size,
                              hipStream_t stream) {
  const float* x   = (const float*)d_in[0];
  const float* W1  = (const float*)d_in[1];
  const float* as1 = (const float*)d_in[2];
  const float* ad1 = (const float*)d_in[3];
  const float* b1  = (const float*)d_in[4];
  const float* W2  = (const float*)d_in[5];
  const float* as2 = (const float*)d_in[6];
  const float* ad2 = (const float*)d_in[7];
  const float* b2  = (const float*)d_in[8];
  const float* fcW = (const float*)d_in[9];
  const float* fcb = (const float*)d_in[10];

  float* ws = (float*)d_ws;
  size_t off = 0;
  auto alloc = [&](size_t nfloats) { float* p = ws + off; off += nfloats; return p; };

  float* h1  = alloc((size_t)NNODE * 512);
  float* x2f = alloc((size_t)NNODE * 256 + 64 + 16384);  // x2b bf16 + W2t bf16
  float* h2  = alloc((size_t)NNODE * 128);
  float* x3  = alloc((size_t)NNODE * 128);
  float* s1  = alloc((size_t)4 * NNODE);
  float* t1  = alloc((size_t)4 * NNODE);
  float* sS1 = alloc((size_t)4 * NNODE);
  int*   sI1 = (int*)alloc((size_t)4 * NNODE);
  int*   qL1 = (int*)alloc((size_t)4 * NNODE);
  float* SS1 = alloc((size_t)4 * (NNODE + 1) * TW);
  float* PP1 = alloc((size_t)4 * (NNODE + 1) * TW);
  float* pP1 = alloc((size_t)4 * NCHUNK * TW);
  float* pM1 = alloc((size_t)4 * NCHUNK * TW);
  float* fP1 = alloc((size_t)4 * NCHUNK * TW);   // suffix of P
  float* fM1 = alloc((size_t)4 * NCHUNK * TW);   // prefix of M
  float* s2  = alloc(NNODE);
  float* t2  = alloc(NNODE);
  float* sS2 = alloc(NNODE);
  int*   sI2 = (int*)alloc(NNODE);
  int*   qL2 = (int*)alloc(NNODE);
  float* SS2 = alloc((size_t)(NNODE + 1) * TW);
  float* PP2 = alloc((size_t)(NNODE + 1) * TW);
  float* pP2 = alloc((size_t)NCHUNK * TW);
  float* pM2 = alloc((size_t)NCHUNK * TW);
  float* fP2 = alloc((size_t)NCHUNK * TW);
  float* fM2 = alloc((size_t)NCHUNK * TW);
  float* mpart = alloc((size_t)64 * CDIM);  // mean partial sums

  // bf16 staging aliased into PP1/SS1 (first written by passC1, strictly after
  // gemm1 last reads them — stream ordered).
  unsigned short* xb  = (unsigned short*)PP1;  // 4096x768 bf16 = 6.3 MB (< 8.65 MB)
  unsigned short* W1t = (unsigned short*)SS1;  // 512x768 bf16
  unsigned short* x2b = (unsigned short*)x2f;                       // 4096x512 bf16
  unsigned short* W2t = (unsigned short*)(x2f + NNODE * 256 + 64);  // 128x512 bf16

  // Prep: convert x + transpose/cast W1, W2 + zero s/t accumulators
  prep_kernel<<<3224, 256, 0, stream>>>(x, W1, W2, xb, W1t, W2t, s1, s2);
  // Layer 1 (64x64 tiles -> 512 blocks; fused s/t epilogue)
  mfma_gemm_bt<64, 64><<<dim3(512 / 64, NNODE / 64), 256, 0, stream>>>(
      xb, W1t, h1, NNODE, 512, 768, s1, t1, as1, ad1);
  rank_sort_kernel<<<dim3(NNODE / 32, 4), 256, 0, stream>>>(s1, t1, sS1, sI1, qL1);
  passA_kernel<<<4 * NCHUNK, 128, 0, stream>>>(h1, sS1, sI1, pP1, pM1, 4);
  passB_kernel<<<dim3(2, 4), 192, 0, stream>>>(pP1, pM1, fP1, fM1);
  passC_kernel<<<4 * NCHUNK, 128, 0, stream>>>(h1, sS1, sI1, fP1, fM1, SS1, PP1, 4);
  attend_kernel<unsigned short><<<NNODE * 4, 128, 0, stream>>>(SS1, PP1, qL1, t1, b1, x2b, 4);
  // Layer 2 (32x64 tiles -> 256 blocks; fused s/t epilogue)
  mfma_gemm_bt<32, 64><<<dim3(128 / 64, NNODE / 32), 256, 0, stream>>>(
      x2b, W2t, h2, NNODE, 128, 512, s2, t2, as2, ad2);
  rank_sort_kernel<<<dim3(NNODE / 32, 1), 256, 0, stream>>>(s2, t2, sS2, sI2, qL2);
  passA_kernel<<<NCHUNK, 128, 0, stream>>>(h2, sS2, sI2, pP2, pM2, 1);
  passB_kernel<<<dim3(2, 1), 192, 0, stream>>>(pP2, pM2, fP2, fM2);
  passC_kernel<<<NCHUNK, 128, 0, stream>>>(h2, sS2, sI2, fP2, fM2, SS2, PP2, 1);
  attend_kernel<float><<<NNODE, 128, 0, stream>>>(SS2, PP2, qL2, t2, b2, x3, 1);
  // Readout: coalesced mean partials + fc
  mean_part_kernel<<<64, 256, 0, stream>>>(x3, mpart);
  fc_kernel<<<3, 256, 0, stream>>>(mpart, fcW, fcb, (float*)d_out);
}